// Round 2
// baseline (648.440 us; speedup 1.0000x reference)
//
#include <hip/hip_runtime.h>
#include <hip/hip_bf16.h>

// Problem constants
#define B_ 64
#define S_ 128
#define C_ 32
#define D_ 512
#define V_ 20000

typedef float     f32x4  __attribute__((ext_vector_type(4)));
typedef _Float16  f16x8  __attribute__((ext_vector_type(8)));

#define AS1 __attribute__((address_space(1)))
#define AS3 __attribute__((address_space(3)))

// ---- workspace layout (bytes) ----
#define OFF_XH   0ull          // fp16 x   [8192][512]    8,388,608
#define OFF_UH   8388608ull    // fp16 U   [2048][512]    2,097,152
#define OFF_AW   10485760ull   // fp16 MFMA A-frag weights [32mm][5tile][2kh][8kt][64ln] = 2,621,440
#define OFF_CB   13631488ull   // f32 cb[2048]                8,192
#define OFF_PAD  13639680ull   // 8 KB pad (unused)
#define OFF_TWT  13647872ull   // f32 timew^T [64][512]     131,072
#define OFF_EMBH 13778944ull   // fp16 emb [20001][512]  20,481,024
#define OFF_TF   34259968ull   // fp16 tf [8192][512]     8,388,608
#define OFF_UX   42648576ull   // fp16 ux [8192][2048]   33,554,432
#define OFF_XB2  76203008ull   // u64 xb[128][32 gid][512 d] = 16,777,216 (self-flagging)
                               // total 92,980,224 B

#define SENT32 0x7FFF7FFFu     // two fp16 NaNs — never produced by finite (h,c) pack

// ---------------- fused prep kernel (segmented by blockIdx) ----------------
// SEG0 [0,1): d_out init with bias
// SEG1 [1,4097): sentinel fill 16 MB
// SEG2 [4097,4098): cb = Wallb + Uallb
// SEG3 [4098,4130): timew^T
// SEG4 [4130,5154): U fp32->fp16
// SEG5 [5154,5794): W_all/W_d -> per-(mm,tile,khalf) MFMA A-frags (dense, no pad)
// SEG6 [5794,25795): emb fp32->fp16
__global__ void k_prep_fused(
    const float* __restrict__ outb, float* __restrict__ outv,
    int4* __restrict__ fillp,
    const float* __restrict__ Wallb, const float* __restrict__ Uallb,
    float* __restrict__ cb,
    const float* __restrict__ tw, float* __restrict__ twt,
    const float* __restrict__ U, _Float16* __restrict__ uh,
    const float* __restrict__ Wall, const float* __restrict__ Wd,
    int4* __restrict__ AW,
    const float* __restrict__ emb, _Float16* __restrict__ eh)
{
    const int blk = blockIdx.x;
    const int t   = threadIdx.x;
    if (blk < 1) {
        if (t < 128) outv[t] = outb[t & 1];
    } else if (blk < 4097) {
        fillp[(blk - 1) * 256 + t] =
            int4{(int)SENT32, (int)SENT32, (int)SENT32, (int)SENT32};
    } else if (blk < 4098) {
        #pragma unroll
        for (int k = 0; k < 8; k++) {
            int i = t * 8 + k;
            cb[i] = Wallb[i] + Uallb[i];
        }
    } else if (blk < 4130) {
        int i2 = (blk - 4098) * 256 + t;
        #pragma unroll
        for (int k = 0; k < 4; k++) {
            int i = i2 * 4 + k;              // 0..32767
            twt[(i & 63) * 512 + (i >> 6)] = tw[i];
        }
    } else if (blk < 5154) {
        int i = (blk - 4130) * 256 + t;      // 0..262143 float4 groups
        float4 v = ((const float4*)U)[i];
        union { _Float16 h[4]; unsigned long long u; } pk;
        pk.h[0] = (_Float16)v.x; pk.h[1] = (_Float16)v.y;
        pk.h[2] = (_Float16)v.z; pk.h[3] = (_Float16)v.w;
        ((unsigned long long*)uh)[i] = pk.u;
    } else if (blk < 5794) {
        int i = (blk - 5154) * 256 + t;      // 0..163839 int4 frags
        int lane = i & 63;  int r = i >> 6;  // 0..2559
        int ktl   = r & 7;  int r2 = r >> 3;
        int khalf = r2 & 1; int r3 = r2 >> 1;
        int tile  = r3 % 5; int mm = r3 / 5; // tile: 0=f 1=i 2=o 3=c~ 4=wd
        int row16 = lane & 15, q4 = lane >> 4;
        int d  = mm * 16 + row16;
        int k0 = khalf * 256 + ktl * 32 + q4 * 8;
        const float* src = (tile < 4) ? (Wall + (size_t)(tile * 512 + d) * 512 + k0)
                                      : (Wd   + (size_t)d * 512 + k0);
        union { _Float16 h[8]; int4 v; } u;
        #pragma unroll
        for (int j = 0; j < 8; j++) u.h[j] = (_Float16)src[j];
        AW[i] = u.v;
    } else {
        int i = (blk - 5794) * 256 + t;      // pair index, 0..5120255
        float2 v = ((const float2*)emb)[i];
        unsigned short hx = __builtin_bit_cast(unsigned short, (_Float16)v.x);
        unsigned short hy = __builtin_bit_cast(unsigned short, (_Float16)v.y);
        ((unsigned*)eh)[i] = (unsigned)hx | ((unsigned)hy << 16);
    }
}

// ---------------- embedding gather-sum (fp16 table) -> x fp16 ----------------
__global__ void k_embed2(const _Float16* __restrict__ embh, const int* __restrict__ seqs,
                         _Float16* __restrict__ xh)
{
    int bs = blockIdx.x;           // b*S + s
    int t  = threadIdx.x;          // 256 threads, 2 halves each
    __shared__ int rows[32];
    if (t < 32) {
        int r = seqs[(size_t)bs * C_ + t];
        rows[t] = (r < 0) ? V_ : r;
    }
    __syncthreads();
    float ax = 0.f, ay = 0.f;
    #pragma unroll 4
    for (int c = 0; c < C_; c++) {
        unsigned v = *(const unsigned*)(embh + (size_t)rows[c] * D_ + 2 * t);
        ax += (float)__builtin_bit_cast(_Float16, (unsigned short)v);
        ay += (float)__builtin_bit_cast(_Float16, (unsigned short)(v >> 16));
    }
    unsigned short hx = __builtin_bit_cast(unsigned short, (_Float16)ax);
    unsigned short hy = __builtin_bit_cast(unsigned short, (_Float16)ay);
    *(unsigned*)(xh + (size_t)bs * D_ + 2 * t) = (unsigned)hx | ((unsigned)hy << 16);
}

// ---------------- time feature: 16 bs per block, thread-per-d ----------------
__global__ __launch_bounds__(512) void k_tf2(
    const float* __restrict__ stime, const float* __restrict__ selw,
    const float* __restrict__ selb, const float* __restrict__ twT,
    const float* __restrict__ timeb, _Float16* __restrict__ tf)
{
    int bb = blockIdx.x;           // covers bs = bb*16 .. bb*16+15
    int t  = threadIdx.x;          // 512
    __shared__ float s1[16][64];
    for (int idx = t; idx < 1024; idx += 512) {
        int bl = idx >> 6, j = idx & 63;
        float tv = stime[bb * 16 + bl] * (1.0f / 180.0f);
        float u  = tv * selw[j] + selb[j];
        s1[bl][j] = 1.0f - tanhf(u * u);
    }
    __syncthreads();
    int d = t;
    float acc[16];
    float tb = timeb[d];
    #pragma unroll
    for (int l = 0; l < 16; l++) acc[l] = tb;
    for (int j = 0; j < 64; j++) {
        float wj = twT[j * 512 + d];
        #pragma unroll
        for (int l = 0; l < 16; l++) acc[l] = fmaf(s1[l][j], wj, acc[l]);
    }
    #pragma unroll
    for (int l = 0; l < 16; l++)
        tf[(size_t)(bb * 16 + l) * 512 + d] = (_Float16)acc[l];
}

// ---------------- ux GEMM v3: m97-style LDS-staged, 128x128 tile, BK=64 --------
__device__ __forceinline__ void stage16(const _Float16* g, _Float16* l)
{
#if __has_builtin(__builtin_amdgcn_global_load_lds)
    __builtin_amdgcn_global_load_lds((const AS1 void*)g, (AS3 void*)l, 16, 0, 0);
#else
    *(int4*)l = *(const int4*)g;
#endif
}

__global__ __launch_bounds__(256, 4) void k_gemm3(const _Float16* __restrict__ A,
                                                  const _Float16* __restrict__ Bm,
                                                  _Float16* __restrict__ Cg)
{
    __shared__ __align__(16) _Float16 As[128 * 64];
    __shared__ __align__(16) _Float16 Bs[128 * 64];
    const int t = threadIdx.x;
    const int w = t >> 6, lane = t & 63;
    const int wm = w & 1, wn = w >> 1;
    const int m0 = blockIdx.y * 128, n0 = blockIdx.x * 128;
    const int r16 = lane & 15, quad = lane >> 4;

    const int srow = w * 8 + (lane >> 3);
    const int k8g  = (lane & 7) ^ ((lane >> 3) & 7);   // swizzled global k8
    const _Float16* ga = A  + (size_t)(m0 + srow) * 512 + k8g * 8;
    const _Float16* gb = Bm + (size_t)(n0 + srow) * 512 + k8g * 8;
    _Float16* la = As + srow * 64 + (lane & 7) * 8;
    _Float16* lb = Bs + srow * 64 + (lane & 7) * 8;

    f32x4 acc[4][4] = {};
    for (int k0 = 0; k0 < 512; k0 += 64) {
        __syncthreads();
        #pragma unroll
        for (int r = 0; r < 4; r++) {
            stage16(ga + k0 + (size_t)r * 32 * 512, la + r * 32 * 64);
            stage16(gb + k0 + (size_t)r * 32 * 512, lb + r * 32 * 64);
        }
        __syncthreads();
        #pragma unroll
        for (int sub = 0; sub < 2; sub++) {
            f16x8 af[4], bf[4];
            const int ksl = ((sub * 4 + quad) ^ (r16 & 7)) * 8;
            #pragma unroll
            for (int i = 0; i < 4; i++) {
                af[i] = *(const f16x8*)(As + (wm * 64 + i * 16 + r16) * 64 + ksl);
                bf[i] = *(const f16x8*)(Bs + (wn * 64 + i * 16 + r16) * 64 + ksl);
            }
            #pragma unroll
            for (int i = 0; i < 4; i++)
                #pragma unroll
                for (int j = 0; j < 4; j++)
                    acc[i][j] = __builtin_amdgcn_mfma_f32_16x16x32_f16(
                                    af[i], bf[j], acc[i][j], 0, 0, 0);
        }
    }
    #pragma unroll
    for (int i = 0; i < 4; i++)
        #pragma unroll
        for (int j = 0; j < 4; j++) {
            int row = m0 + wm * 64 + i * 16 + quad * 4;
            int col = n0 + wn * 64 + j * 16 + r16;
            _Float16* cp = Cg + (size_t)row * 2048 + col;
            #pragma unroll
            for (int rg = 0; rg < 4; rg++)
                cp[(size_t)rg * 2048] = (_Float16)acc[i][j][rg];
        }
}

// ---------------- fast transcendentals (v_exp + v_rcp) ----------------
__device__ __forceinline__ float fsigm(float x)
{
    return __builtin_amdgcn_rcpf(1.f + __expf(-x));
}
__device__ __forceinline__ float ftanh(float x)
{
    return 1.f - 2.f * __builtin_amdgcn_rcpf(1.f + __expf(2.f * x));
}

// ---------------- recurrence v9: dense 16-col B, thin d16 slices, 256 blocks ----
// Block (g, mm): group g (batches g*8..g*8+7), output d-slice mm*16..mm*16+15.
// blockIdx = g*32+mm -> consecutive mm spread across XCDs (rnn7 property).
// 10 waves: wave = (tile 0..4, khalf); 8 MFMAs/wave/step (vs rnn7's 48):
// MFMA phase ~300cyc. B = 16 streams {h,c}x8 batches, full k=512 staged in LDS.
// Poll: 512 threads x 4 CONSECUTIVE u64 (32B, one producer store) -> single
// visibility event. Stage = 4 packed ds_write_b64/thread. 2 barriers/step.
// xb layout unchanged: xb[s][gid 0..31][d 0..511] u64 = (h_b0,c_b0,h_b1,c_b1).
__global__ __launch_bounds__(640, 1) void k_rnn9(
    const int4* __restrict__ AW,
    const float* __restrict__ cbv, const float* __restrict__ wdb,
    const _Float16* __restrict__ ux, const _Float16* __restrict__ tf,
    const float* __restrict__ outw,
    float* __restrict__ out,
    unsigned long long* __restrict__ xb64)
{
    const int t    = threadIdx.x;
    const int g    = blockIdx.x >> 5;   // group 0..7
    const int mm   = blockIdx.x & 31;   // d16 slice
    const int w    = t >> 6;            // wave 0..9
    const int lane = t & 63;
    const int col  = lane & 15;
    const int quad = lane >> 4;
    const int tile = w >> 1, khalf = w & 1;

    // A-fragments: tile (16 rows at d=mm*16+row16) x k-half (256), 8 ksteps
    int4 Af[8];
    {
        const int4* src = AW + (size_t)(((mm * 5 + tile) * 2 + khalf) * 8) * 64;
        #pragma unroll
        for (int i = 0; i < 8; i++) Af[i] = src[i * 64 + lane];
    }

    __shared__ __align__(16) _Float16 xstg[16 * 520];   // 16 streams, stride 520
    __shared__ __align__(16) float cmat[5][2][16][20];  // [tile][khalf][col][row16]

    // activation role: 128 threads = 8 batches x 16 d
    const bool act = (t < 128);
    const int bl   = t >> 4;            // local batch 0..7
    const int d16  = t & 15;
    const int gg   = bl >> 1, pb = bl & 1;
    const int dg   = mm * 16 + d16;     // global d
    const int batch = g * 8 + bl;
    const int hcol = gg * 4 + pb;       // h stream for this batch
    const int ccol = gg * 4 + 2 + pb;   // c stream

    float cbf = 0, cbi = 0, cbo = 0, cbc = 0, bdv = 0;
    if (act) {
        cbf = cbv[dg]; cbi = cbv[512 + dg]; cbo = cbv[1024 + dg]; cbc = cbv[1536 + dg];
        bdv = wdb[dg];
    }
    float c_reg = 0.f, pool = -1e30f;

    // staging role: 512 threads x 4 consecutive u64 covering group region
    const bool stg = (t < 512);
    const int  k0  = (t * 4) & 511;     // k index (= producer d) of first u64
    const int  sgg = t >> 7;            // gid-within-group of staged data
    const size_t pboff = (size_t)g * 2048 + (size_t)t * 4;

    for (int s = 0; s < S_; s++) {
        unsigned long long v0 = 0, v1 = 0, v2 = 0, v3 = 0;
        if (stg && s > 0) {
            const unsigned long long* sp = xb64 + (size_t)s * 16384 + pboff;
            int tries = 0;
            for (;;) {
                v0 = __hip_atomic_load(sp + 0, __ATOMIC_RELAXED, __HIP_MEMORY_SCOPE_AGENT);
                v1 = __hip_atomic_load(sp + 1, __ATOMIC_RELAXED, __HIP_MEMORY_SCOPE_AGENT);
                v2 = __hip_atomic_load(sp + 2, __ATOMIC_RELAXED, __HIP_MEMORY_SCOPE_AGENT);
                v3 = __hip_atomic_load(sp + 3, __ATOMIC_RELAXED, __HIP_MEMORY_SCOPE_AGENT);
                if ((unsigned)v0 != SENT32 && (unsigned)v1 != SENT32 &&
                    (unsigned)v2 != SENT32 && (unsigned)v3 != SENT32)
                    break;
                if (++tries > (1 << 22)) break;   // safety valve
            }
        }
        if (stg) {
            // repack 4 u64 (4 consecutive k of one gid) into 4 stream-u64s
            unsigned long long h0 = (v0 & 0xFFFFull)         | ((v1 & 0xFFFFull) << 16)
                                  | ((v2 & 0xFFFFull) << 32) | ((v3 & 0xFFFFull) << 48);
            unsigned long long c0 = ((v0 >> 16) & 0xFFFFull)         | (((v1 >> 16) & 0xFFFFull) << 16)
                                  | (((v2 >> 16) & 0xFFFFull) << 32) | (((v3 >> 16) & 0xFFFFull) << 48);
            unsigned long long h1 = ((v0 >> 32) & 0xFFFFull)         | (((v1 >> 32) & 0xFFFFull) << 16)
                                  | (((v2 >> 32) & 0xFFFFull) << 32) | (((v3 >> 32) & 0xFFFFull) << 48);
            unsigned long long c1 = (v0 >> 48)          | ((v1 >> 48) << 16)
                                  | ((v2 >> 48) << 32)  | ((v3 >> 48) << 48);
            *(unsigned long long*)(xstg + (sgg * 4 + 0) * 520 + k0) = h0;
            *(unsigned long long*)(xstg + (sgg * 4 + 1) * 520 + k0) = h1;
            *(unsigned long long*)(xstg + (sgg * 4 + 2) * 520 + k0) = c0;
            *(unsigned long long*)(xstg + (sgg * 4 + 3) * 520 + k0) = c1;
        }
        __syncthreads();               // B1: staging visible (also: cmat free)

        // act operands issued early — latency hides under MFMA phase
        float uf = 0, ui = 0, uo = 0, uc = 0, tv = 0;
        if (act) {
            const _Float16* up = ux + ((size_t)batch * S_ + s) * 2048 + dg;
            uf = (float)up[0];    ui = (float)up[512];
            uo = (float)up[1024]; uc = (float)up[1536];
            tv = (float)tf[((size_t)batch * S_ + s) * 512 + dg];
        }

        f32x4 a = {0, 0, 0, 0};
        #pragma unroll
        for (int kt = 0; kt < 8; kt++) {
            f16x8 b = *(const f16x8*)(xstg + col * 520 + (khalf * 8 + kt) * 32 + quad * 8);
            a = __builtin_amdgcn_mfma_f32_16x16x32_f16(
                    __builtin_bit_cast(f16x8, Af[kt]), b, a, 0, 0, 0);
        }
        *(f32x4*)&cmat[tile][khalf][col][quad * 4] = a;
        __syncthreads();               // B3: cmat visible (also: xstg free)

        if (act) {
            float f_  = cmat[0][0][hcol][d16] + cmat[0][1][hcol][d16];
            float i_  = cmat[1][0][hcol][d16] + cmat[1][1][hcol][d16];
            float o_  = cmat[2][0][hcol][d16] + cmat[2][1][hcol][d16];
            float g_  = cmat[3][0][hcol][d16] + cmat[3][1][hcol][d16];
            float wd_ = cmat[4][0][ccol][d16] + cmat[4][1][ccol][d16];
            float gf = fsigm(f_ + cbf + uf);
            float gi = fsigm(i_ + cbi + ui);
            float go = fsigm(o_ + cbo + uo);
            float gc = fsigm(g_ + cbc + uc);
            float cs1  = ftanh(wd_ + bdv);
            float cadj = c_reg - cs1 + cs1 * tv;
            float cn   = gf * cadj + gi * gc;
            float hn   = go * ftanh(cn);
            c_reg = cn;
            pool  = fmaxf(pool, hn);
            unsigned hh  = __builtin_bit_cast(unsigned short, (_Float16)hn);
            unsigned chn = __builtin_bit_cast(unsigned short, (_Float16)cn);
            unsigned pk  = hh | (chn << 16);
            unsigned other = __shfl(pk, lane + 16);   // partner batch (pb=1), same d
            if (pb == 0 && s != S_ - 1) {
                unsigned long long ov =
                    (unsigned long long)pk | ((unsigned long long)other << 32);
                unsigned long long* dst =
                    xb64 + (size_t)(s + 1) * 16384 + (size_t)(g * 4 + gg) * 512 + dg;
                __hip_atomic_store(dst, ov, __ATOMIC_RELAXED,
                                   __HIP_MEMORY_SCOPE_AGENT);
            }
        }
    }

    // pooled epilogue: reduce 16 d per batch, atomicAdd into bias-inited d_out
    if (act) {
        float p0 = pool * outw[dg], p1 = pool * outw[512 + dg];
        #pragma unroll
        for (int off = 8; off > 0; off >>= 1) {
            p0 += __shfl_down(p0, off, 16);
            p1 += __shfl_down(p1, off, 16);
        }
        if (d16 == 0) {
            atomicAdd(&out[2 * batch],     p0);
            atomicAdd(&out[2 * batch + 1], p1);
        }
    }
}

// ---------------- launch ----------------
extern "C" void kernel_launch(void* const* d_in, const int* in_sizes, int n_in,
                              void* d_out, int out_size, void* d_ws, size_t ws_size,
                              hipStream_t stream)
{
    const float* emb   = (const float*)d_in[0];
    const float* Wall  = (const float*)d_in[1];
    const float* Wallb = (const float*)d_in[2];
    const float* Uall  = (const float*)d_in[3];
    const float* Uallb = (const float*)d_in[4];
    const float* Wdw   = (const float*)d_in[5];
    const float* Wdb   = (const float*)d_in[6];
    const float* selw  = (const float*)d_in[7];
    const float* selb  = (const float*)d_in[8];
    const float* timew = (const float*)d_in[9];
    const float* timeb = (const float*)d_in[10];
    const float* outw  = (const float*)d_in[11];
    const float* outb  = (const float*)d_in[12];
    const float* stime = (const float*)d_in[13];
    const int*   seqs  = (const int*)d_in[14];
    float* out = (float*)d_out;
    char*  ws  = (char*)d_ws;

    _Float16* xh   = (_Float16*)(ws + OFF_XH);
    _Float16* uh   = (_Float16*)(ws + OFF_UH);
    int4*     aw   = (int4*)(ws + OFF_AW);
    float*    cbp  = (float*)(ws + OFF_CB);
    float*    twt  = (float*)(ws + OFF_TWT);
    _Float16* eh   = (_Float16*)(ws + OFF_EMBH);
    _Float16* tfp  = (_Float16*)(ws + OFF_TF);
    _Float16* uxp  = (_Float16*)(ws + OFF_UX);
    unsigned long long* xb = (unsigned long long*)(ws + OFF_XB2);

    k_prep_fused<<<25795, 256, 0, stream>>>(
        outb, out, (int4*)(ws + OFF_XB2),
        Wallb, Uallb, cbp,
        timew, twt,
        Uall, uh,
        Wall, Wdw, aw,
        emb, eh);
    k_embed2 <<<B_ * S_, 256, 0, stream>>>(eh, seqs, xh);
    k_tf2    <<<512,     512, 0, stream>>>(stime, selw, selb, twt, timeb, tfp);
    k_gemm3  <<<dim3(16, 64), 256, 0, stream>>>(xh, uh, uxp);
    k_rnn9   <<<256,     640, 0, stream>>>(aw, cbp, Wdb, uxp, tfp, outw, out, xb);
}